// Round 1
// 1248.775 us; speedup vs baseline: 1.0056x; 1.0056x over previous
//
#include <hip/hip_runtime.h>
#include <stdint.h>

// HashGridEncoding: tcnn hashgrid (L=16, F=2, T=2^19, base=16, scale=1.5)
// fused with Linear(32 -> 64). fp32 in/out.
//
// Phase 1: one thread per point, 16 levels x 8 float2 gathers, trilinear interp.
// Phase 2: enc staged through LDS; each wave: lane -> output channel j (j and j+32),
//          W rows in VGPRs, enc broadcast-read from LDS, fully coalesced stores.
//
// R1 changes vs baseline (1046 us, FETCH 3.46 GB >> 64 MB table):
//  - NON-TEMPORAL stores for out (256 MB/dispatch was streaming through L3 and
//    evicting the 64 MB hash table -> 3.4 GB HBM re-fetch). nt keeps table L3-resident.
//  - nt loads for x (read-once stream, don't pollute).
//  - LDS 36KB -> 32KB via XOR-swizzled float4 slots (writes stay conflict-free,
//    reads are half-wave broadcasts so swizzle is uniform) -> 5 blocks/CU instead of 4.
//  - __launch_bounds__(256,5) to pin VGPR <= 102 (baseline used 92).

constexpr int LVLS = 16;
constexpr uint32_t TSIZE = 1u << 19;
constexpr int RAW = 32;   // L*F
constexpr int ODIM = 64;

__device__ __forceinline__ uint32_t umin32(uint32_t a, uint32_t b) { return a < b ? a : b; }

__global__ __launch_bounds__(256, 5) void hashgrid_fused(
    const float* __restrict__ x,
    const float* __restrict__ table,
    const float* __restrict__ W,
    const float* __restrict__ bias,
    float* __restrict__ out)
{
    // scale_l = 16*1.5^l - 1 (exactly representable in f32); res_l = ceil(scale)+1
    static constexpr float kScale[LVLS] = {
        15.0f, 23.0f, 35.0f, 53.0f, 80.0f, 120.5f, 181.25f, 272.375f,
        409.0625f, 614.09375f, 921.640625f, 1382.9609375f,
        2074.94140625f, 3112.912109375f, 4669.8681640625f, 7005.30224609375f};
    static constexpr uint32_t kRes[LVLS] = {
        16, 24, 36, 54, 81, 122, 183, 274, 411, 616, 923, 1384, 2076, 3114, 4671, 7007};
    // levels 0..3 dense (res^3 <= T), 4..15 hashed

    // 256 rows x 32 floats (128B). float4 slot k of row r lives at slot (k ^ (r&7)):
    // writes: lanes i..i+7 hit distinct bank quads; reads: half-wave-uniform address.
    __shared__ float encS[256 * 32];  // 32 KiB -> 5 blocks/CU

    const int tid = threadIdx.x;
    const int p = blockIdx.x * 256 + tid;   // P is an exact multiple of 256

    float enc[RAW];

    {
        const float xr0 = __builtin_nontemporal_load(&x[3 * p + 0]);
        const float xr1 = __builtin_nontemporal_load(&x[3 * p + 1]);
        const float xr2 = __builtin_nontemporal_load(&x[3 * p + 2]);
        const float xn0 = (xr0 + 1.0f) * 0.5f;
        const float xn1 = (xr1 + 1.0f) * 0.5f;
        const float xn2 = (xr2 + 1.0f) * 0.5f;

#pragma unroll
        for (int l = 0; l < LVLS; ++l) {
            const float s = kScale[l];
            const uint32_t res = kRes[l];

            const float pa = xn0 * s + 0.5f;
            const float pb = xn1 * s + 0.5f;
            const float pc = xn2 * s + 0.5f;
            const float fa = floorf(pa);
            const float fb = floorf(pb);
            const float fc = floorf(pc);
            const float ra = pa - fa;
            const float rb = pb - fb;
            const float rc = pc - fc;
            const uint32_t ca = (uint32_t)fa;
            const uint32_t cb = (uint32_t)fb;
            const uint32_t cc = (uint32_t)fc;

            uint32_t idx[8];
            if (l < 4) {
                // dense: idx = cx + cy*res + cz*res^2, coords clamped to res-1
                const uint32_t rm = res - 1u;
                const uint32_t rr = res * res;
                const uint32_t x0 = umin32(ca, rm);
                const uint32_t x1 = umin32(ca + 1u, rm);
                const uint32_t y0 = umin32(cb, rm) * res;
                const uint32_t y1 = umin32(cb + 1u, rm) * res;
                const uint32_t z0 = umin32(cc, rm) * rr;
                const uint32_t z1 = umin32(cc + 1u, rm) * rr;
                idx[0] = x0 + y0 + z0;
                idx[1] = x0 + y0 + z1;
                idx[2] = x0 + y1 + z0;
                idx[3] = x0 + y1 + z1;
                idx[4] = x1 + y0 + z0;
                idx[5] = x1 + y0 + z1;
                idx[6] = x1 + y1 + z0;
                idx[7] = x1 + y1 + z1;
            } else {
                // hashed: (cx*1) ^ (cy*2654435761) ^ (cz*805459861), mod T
                const uint32_t hx0 = ca;
                const uint32_t hx1 = ca + 1u;
                const uint32_t hy0 = cb * 2654435761u;
                const uint32_t hy1 = hy0 + 2654435761u;
                const uint32_t hz0 = cc * 805459861u;
                const uint32_t hz1 = hz0 + 805459861u;
                idx[0] = (hx0 ^ hy0 ^ hz0) & (TSIZE - 1u);
                idx[1] = (hx0 ^ hy0 ^ hz1) & (TSIZE - 1u);
                idx[2] = (hx0 ^ hy1 ^ hz0) & (TSIZE - 1u);
                idx[3] = (hx0 ^ hy1 ^ hz1) & (TSIZE - 1u);
                idx[4] = (hx1 ^ hy0 ^ hz0) & (TSIZE - 1u);
                idx[5] = (hx1 ^ hy0 ^ hz1) & (TSIZE - 1u);
                idx[6] = (hx1 ^ hy1 ^ hz0) & (TSIZE - 1u);
                idx[7] = (hx1 ^ hy1 ^ hz1) & (TSIZE - 1u);
            }

            const float2* tl = reinterpret_cast<const float2*>(table) + (size_t)l * TSIZE;
            float2 g[8];
#pragma unroll
            for (int k = 0; k < 8; ++k) g[k] = tl[idx[k]];

            const float wa0 = 1.0f - ra, wa1 = ra;
            const float wb0 = 1.0f - rb, wb1 = rb;
            const float wc0 = 1.0f - rc, wc1 = rc;
            float e0 = 0.0f, e1 = 0.0f;
#pragma unroll
            for (int k = 0; k < 8; ++k) {
                const float w = ((k & 4) ? wa1 : wa0) * ((k & 2) ? wb1 : wb0) * ((k & 1) ? wc1 : wc0);
                e0 = fmaf(w, g[k].x, e0);
                e1 = fmaf(w, g[k].y, e1);
            }
            enc[2 * l] = e0;
            enc[2 * l + 1] = e1;
        }
    }

    // stage enc -> LDS: row tid, float4 slot k stored at (k ^ (tid&7))
    {
        float4* encV = reinterpret_cast<float4*>(enc);
        float4* row = reinterpret_cast<float4*>(&encS[tid * 32]);
        const int sw = tid & 7;
#pragma unroll
        for (int k = 0; k < 8; ++k) row[k ^ sw] = encV[k];
    }

    // per-lane W rows (j0 and j0+32) into VGPRs; issued before barrier to hide latency
    const int lane = tid & 63;
    const int wv = tid >> 6;
    const int j0 = lane & 31;
    const int half = lane >> 5;

    float Wreg0[RAW], Wreg1[RAW];
    {
        const float4* W4 = reinterpret_cast<const float4*>(W);
        float4* w0 = reinterpret_cast<float4*>(Wreg0);
        float4* w1 = reinterpret_cast<float4*>(Wreg1);
#pragma unroll
        for (int k = 0; k < 8; ++k) {
            w0[k] = W4[j0 * 8 + k];
            w1[k] = W4[(j0 + 32) * 8 + k];
        }
    }
    const float b0 = bias[j0];
    const float b1 = bias[j0 + 32];

    __syncthreads();

    // phase 2: wave wv covers block-local points [wv*64, wv*64+64)
    // lane half h handles point 2i+h; lane's channels are j0 and j0+32.
    const size_t outBase = (size_t)blockIdx.x * 256 * ODIM;
#pragma unroll 2
    for (int i = 0; i < 32; ++i) {
        const int q = wv * 64 + 2 * i + half;
        const float4* er = reinterpret_cast<const float4*>(&encS[q * 32]);
        const int qsw = q & 7;
        float acc0 = b0, acc1 = b1;
#pragma unroll
        for (int k4 = 0; k4 < 8; ++k4) {
            const float4 e = er[k4 ^ qsw];
            acc0 = fmaf(e.x, Wreg0[4 * k4 + 0], acc0);
            acc1 = fmaf(e.x, Wreg1[4 * k4 + 0], acc1);
            acc0 = fmaf(e.y, Wreg0[4 * k4 + 1], acc0);
            acc1 = fmaf(e.y, Wreg1[4 * k4 + 1], acc1);
            acc0 = fmaf(e.z, Wreg0[4 * k4 + 2], acc0);
            acc1 = fmaf(e.z, Wreg1[4 * k4 + 2], acc1);
            acc0 = fmaf(e.w, Wreg0[4 * k4 + 3], acc0);
            acc1 = fmaf(e.w, Wreg1[4 * k4 + 3], acc1);
        }
        // NT stores: out is 256 MB/dispatch write-once -> must not evict the
        // 64 MB hash table from Infinity Cache (this was 3.4 GB of HBM re-fetch).
        float* o = out + outBase + (size_t)q * ODIM;
        __builtin_nontemporal_store(acc0, &o[j0]);
        __builtin_nontemporal_store(acc1, &o[j0 + 32]);
    }
}

extern "C" void kernel_launch(void* const* d_in, const int* in_sizes, int n_in,
                              void* d_out, int out_size, void* d_ws, size_t ws_size,
                              hipStream_t stream) {
    const float* x = (const float*)d_in[0];      // [B,N,3]
    const float* table = (const float*)d_in[1];  // [L,T,F]
    const float* W = (const float*)d_in[2];      // [64,32]
    const float* b = (const float*)d_in[3];      // [64]
    float* out = (float*)d_out;                  // [B,N,64]

    const int P = in_sizes[0] / 3;               // 1048576, multiple of 256
    const int blocks = P / 256;
    hipLaunchKernelGGL(hashgrid_fused, dim3(blocks), dim3(256), 0, stream,
                       x, table, W, b, out);
}

// Round 2
// 1130.485 us; speedup vs baseline: 1.1108x; 1.1046x over previous
//
#include <hip/hip_runtime.h>
#include <stdint.h>

// HashGridEncoding: tcnn hashgrid (L=16, F=2, T=2^19, base=16, scale=1.5)
// fused with Linear(32 -> 64). fp32 in/out.
//
// R2: XCD-level partitioning. The gather working set is 64 MB (16 levels x 4 MB)
// vs 4 MB L2 per XCD -> every hashed gather was an L2 miss; fetch path saturated
// at ~3.6 TB/s (random 64B-line ceiling). Split into two kernels:
//   k1: block (chunk, grp=blockIdx&7) -> XCD grp handles ONLY levels {grp, grp+8}
//       (<=8 MB working set per L2, levels 8-10 fully resident). Writes partial
//       enc [8][P][4] f32 to workspace (nt stores).
//   k2: gathers the 8 partials (coalesced float4 streams), rebuilds enc in natural
//       order (bit-identical FMA sequence), LDS-staged Linear(32->64), nt stores.
// Falls back to the R1 single-kernel if ws_size < 128 MB.

constexpr int LVLS = 16;
constexpr uint32_t TSIZE = 1u << 19;
constexpr int RAW = 32;   // L*F
constexpr int ODIM = 64;

typedef float vfloat4 __attribute__((ext_vector_type(4)));

// scale_l = 16*1.5^l - 1 (exactly representable in f32); res_l = ceil(scale)+1
__constant__ float kScaleC[LVLS] = {
    15.0f, 23.0f, 35.0f, 53.0f, 80.0f, 120.5f, 181.25f, 272.375f,
    409.0625f, 614.09375f, 921.640625f, 1382.9609375f,
    2074.94140625f, 3112.912109375f, 4669.8681640625f, 7005.30224609375f};
__constant__ uint32_t kResC[LVLS] = {
    16, 24, 36, 54, 81, 122, 183, 274, 411, 616, 923, 1384, 2076, 3114, 4671, 7007};

__device__ __forceinline__ uint32_t umin32(uint32_t a, uint32_t b) { return a < b ? a : b; }

// One level's trilinear-interpolated float2 feature. l is wave-uniform.
__device__ __forceinline__ void enc_level(
    int l, float xn0, float xn1, float xn2,
    const float* __restrict__ table, float& e0out, float& e1out)
{
    const float s = kScaleC[l];
    const uint32_t res = kResC[l];

    const float pa = xn0 * s + 0.5f;
    const float pb = xn1 * s + 0.5f;
    const float pc = xn2 * s + 0.5f;
    const float fa = floorf(pa);
    const float fb = floorf(pb);
    const float fc = floorf(pc);
    const float ra = pa - fa;
    const float rb = pb - fb;
    const float rc = pc - fc;
    const uint32_t ca = (uint32_t)fa;
    const uint32_t cb = (uint32_t)fb;
    const uint32_t cc = (uint32_t)fc;

    uint32_t idx[8];
    if (l < 4) {
        // dense: idx = cx + cy*res + cz*res^2, coords clamped to res-1
        const uint32_t rm = res - 1u;
        const uint32_t rr = res * res;
        const uint32_t x0 = umin32(ca, rm);
        const uint32_t x1 = umin32(ca + 1u, rm);
        const uint32_t y0 = umin32(cb, rm) * res;
        const uint32_t y1 = umin32(cb + 1u, rm) * res;
        const uint32_t z0 = umin32(cc, rm) * rr;
        const uint32_t z1 = umin32(cc + 1u, rm) * rr;
        idx[0] = x0 + y0 + z0;
        idx[1] = x0 + y0 + z1;
        idx[2] = x0 + y1 + z0;
        idx[3] = x0 + y1 + z1;
        idx[4] = x1 + y0 + z0;
        idx[5] = x1 + y0 + z1;
        idx[6] = x1 + y1 + z0;
        idx[7] = x1 + y1 + z1;
    } else {
        // hashed: (cx*1) ^ (cy*2654435761) ^ (cz*805459861), mod T
        const uint32_t hx0 = ca;
        const uint32_t hx1 = ca + 1u;
        const uint32_t hy0 = cb * 2654435761u;
        const uint32_t hy1 = hy0 + 2654435761u;
        const uint32_t hz0 = cc * 805459861u;
        const uint32_t hz1 = hz0 + 805459861u;
        idx[0] = (hx0 ^ hy0 ^ hz0) & (TSIZE - 1u);
        idx[1] = (hx0 ^ hy0 ^ hz1) & (TSIZE - 1u);
        idx[2] = (hx0 ^ hy1 ^ hz0) & (TSIZE - 1u);
        idx[3] = (hx0 ^ hy1 ^ hz1) & (TSIZE - 1u);
        idx[4] = (hx1 ^ hy0 ^ hz0) & (TSIZE - 1u);
        idx[5] = (hx1 ^ hy0 ^ hz1) & (TSIZE - 1u);
        idx[6] = (hx1 ^ hy1 ^ hz0) & (TSIZE - 1u);
        idx[7] = (hx1 ^ hy1 ^ hz1) & (TSIZE - 1u);
    }

    const float2* tl = reinterpret_cast<const float2*>(table) + (size_t)l * TSIZE;
    float2 g[8];
#pragma unroll
    for (int k = 0; k < 8; ++k) g[k] = tl[idx[k]];

    const float wa0 = 1.0f - ra, wa1 = ra;
    const float wb0 = 1.0f - rb, wb1 = rb;
    const float wc0 = 1.0f - rc, wc1 = rc;
    float e0 = 0.0f, e1 = 0.0f;
#pragma unroll
    for (int k = 0; k < 8; ++k) {
        const float w = ((k & 4) ? wa1 : wa0) * ((k & 2) ? wb1 : wb0) * ((k & 1) ? wc1 : wc0);
        e0 = fmaf(w, g[k].x, e0);
        e1 = fmaf(w, g[k].y, e1);
    }
    e0out = e0;
    e1out = e1;
}

// Kernel 1: grid (P/256)*8. Block (chunk, grp): grp = blockIdx&7 -> XCD grp
// (dispatch round-robin). XCD grp gathers ONLY levels {grp, grp+8}.
__global__ __launch_bounds__(256) void hashgrid_part(
    const float* __restrict__ x,
    const float* __restrict__ table,
    float* __restrict__ encPart,
    int P)
{
    const int grp = blockIdx.x & 7;
    const int chunk = blockIdx.x >> 3;
    const int tid = threadIdx.x;
    const int p = chunk * 256 + tid;

    const float xr0 = x[3 * p + 0];
    const float xr1 = x[3 * p + 1];
    const float xr2 = x[3 * p + 2];
    const float xn0 = (xr0 + 1.0f) * 0.5f;
    const float xn1 = (xr1 + 1.0f) * 0.5f;
    const float xn2 = (xr2 + 1.0f) * 0.5f;

    float e0, e1, e2, e3;
    enc_level(grp, xn0, xn1, xn2, table, e0, e1);
    enc_level(grp + 8, xn0, xn1, xn2, table, e2, e3);

    vfloat4 v = {e0, e1, e2, e3};
    vfloat4* dst = reinterpret_cast<vfloat4*>(encPart) + (size_t)grp * P + p;
    __builtin_nontemporal_store(v, dst);   // streaming, read-once by k2
}

// Kernel 2: assemble enc (natural order), Linear(32->64) via LDS broadcast.
__global__ __launch_bounds__(256, 5) void linear_out(
    const float* __restrict__ encPart,
    const float* __restrict__ W,
    const float* __restrict__ bias,
    float* __restrict__ out,
    int P)
{
    __shared__ float encS[256 * 32];  // 32 KiB, XOR-swizzled float4 slots

    const int tid = threadIdx.x;
    const int p = blockIdx.x * 256 + tid;

    float enc[RAW];
    {
        const float4* ep = reinterpret_cast<const float4*>(encPart);
#pragma unroll
        for (int g = 0; g < 8; ++g) {
            const float4 v = ep[(size_t)g * P + p];  // coalesced 16B/lane per stream
            enc[2 * g + 0] = v.x;                    // level g
            enc[2 * g + 1] = v.y;
            enc[16 + 2 * g + 0] = v.z;               // level g+8
            enc[16 + 2 * g + 1] = v.w;
        }
    }

    // stage enc -> LDS: row tid, float4 slot k stored at (k ^ (tid&7))
    {
        float4* encV = reinterpret_cast<float4*>(enc);
        float4* row = reinterpret_cast<float4*>(&encS[tid * 32]);
        const int sw = tid & 7;
#pragma unroll
        for (int k = 0; k < 8; ++k) row[k ^ sw] = encV[k];
    }

    // per-lane W rows (j0 and j0+32) into VGPRs
    const int lane = tid & 63;
    const int wv = tid >> 6;
    const int j0 = lane & 31;
    const int half = lane >> 5;

    float Wreg0[RAW], Wreg1[RAW];
    {
        const float4* W4 = reinterpret_cast<const float4*>(W);
        float4* w0 = reinterpret_cast<float4*>(Wreg0);
        float4* w1 = reinterpret_cast<float4*>(Wreg1);
#pragma unroll
        for (int k = 0; k < 8; ++k) {
            w0[k] = W4[j0 * 8 + k];
            w1[k] = W4[(j0 + 32) * 8 + k];
        }
    }
    const float b0 = bias[j0];
    const float b1 = bias[j0 + 32];

    __syncthreads();

    const size_t outBase = (size_t)blockIdx.x * 256 * ODIM;
#pragma unroll 2
    for (int i = 0; i < 32; ++i) {
        const int q = wv * 64 + 2 * i + half;
        const float4* er = reinterpret_cast<const float4*>(&encS[q * 32]);
        const int qsw = q & 7;
        float acc0 = b0, acc1 = b1;
#pragma unroll
        for (int k4 = 0; k4 < 8; ++k4) {
            const float4 e = er[k4 ^ qsw];
            acc0 = fmaf(e.x, Wreg0[4 * k4 + 0], acc0);
            acc1 = fmaf(e.x, Wreg1[4 * k4 + 0], acc1);
            acc0 = fmaf(e.y, Wreg0[4 * k4 + 1], acc0);
            acc1 = fmaf(e.y, Wreg1[4 * k4 + 1], acc1);
            acc0 = fmaf(e.z, Wreg0[4 * k4 + 2], acc0);
            acc1 = fmaf(e.z, Wreg1[4 * k4 + 2], acc1);
            acc0 = fmaf(e.w, Wreg0[4 * k4 + 3], acc0);
            acc1 = fmaf(e.w, Wreg1[4 * k4 + 3], acc1);
        }
        float* o = out + outBase + (size_t)q * ODIM;
        __builtin_nontemporal_store(acc0, &o[j0]);
        __builtin_nontemporal_store(acc1, &o[j0 + 32]);
    }
}

// ---------------- fallback: R1 single-kernel (used if workspace too small) ----

__global__ __launch_bounds__(256, 5) void hashgrid_fused(
    const float* __restrict__ x,
    const float* __restrict__ table,
    const float* __restrict__ W,
    const float* __restrict__ bias,
    float* __restrict__ out)
{
    static constexpr float kScale[LVLS] = {
        15.0f, 23.0f, 35.0f, 53.0f, 80.0f, 120.5f, 181.25f, 272.375f,
        409.0625f, 614.09375f, 921.640625f, 1382.9609375f,
        2074.94140625f, 3112.912109375f, 4669.8681640625f, 7005.30224609375f};
    static constexpr uint32_t kRes[LVLS] = {
        16, 24, 36, 54, 81, 122, 183, 274, 411, 616, 923, 1384, 2076, 3114, 4671, 7007};

    __shared__ float encS[256 * 32];

    const int tid = threadIdx.x;
    const int p = blockIdx.x * 256 + tid;

    float enc[RAW];

    {
        const float xr0 = x[3 * p + 0];
        const float xr1 = x[3 * p + 1];
        const float xr2 = x[3 * p + 2];
        const float xn0 = (xr0 + 1.0f) * 0.5f;
        const float xn1 = (xr1 + 1.0f) * 0.5f;
        const float xn2 = (xr2 + 1.0f) * 0.5f;

#pragma unroll
        for (int l = 0; l < LVLS; ++l) {
            const float s = kScale[l];
            const uint32_t res = kRes[l];

            const float pa = xn0 * s + 0.5f;
            const float pb = xn1 * s + 0.5f;
            const float pc = xn2 * s + 0.5f;
            const float fa = floorf(pa);
            const float fb = floorf(pb);
            const float fc = floorf(pc);
            const float ra = pa - fa;
            const float rb = pb - fb;
            const float rc = pc - fc;
            const uint32_t ca = (uint32_t)fa;
            const uint32_t cb = (uint32_t)fb;
            const uint32_t cc = (uint32_t)fc;

            uint32_t idx[8];
            if (l < 4) {
                const uint32_t rm = res - 1u;
                const uint32_t rr = res * res;
                const uint32_t x0 = umin32(ca, rm);
                const uint32_t x1 = umin32(ca + 1u, rm);
                const uint32_t y0 = umin32(cb, rm) * res;
                const uint32_t y1 = umin32(cb + 1u, rm) * res;
                const uint32_t z0 = umin32(cc, rm) * rr;
                const uint32_t z1 = umin32(cc + 1u, rm) * rr;
                idx[0] = x0 + y0 + z0;
                idx[1] = x0 + y0 + z1;
                idx[2] = x0 + y1 + z0;
                idx[3] = x0 + y1 + z1;
                idx[4] = x1 + y0 + z0;
                idx[5] = x1 + y0 + z1;
                idx[6] = x1 + y1 + z0;
                idx[7] = x1 + y1 + z1;
            } else {
                const uint32_t hx0 = ca;
                const uint32_t hx1 = ca + 1u;
                const uint32_t hy0 = cb * 2654435761u;
                const uint32_t hy1 = hy0 + 2654435761u;
                const uint32_t hz0 = cc * 805459861u;
                const uint32_t hz1 = hz0 + 805459861u;
                idx[0] = (hx0 ^ hy0 ^ hz0) & (TSIZE - 1u);
                idx[1] = (hx0 ^ hy0 ^ hz1) & (TSIZE - 1u);
                idx[2] = (hx0 ^ hy1 ^ hz0) & (TSIZE - 1u);
                idx[3] = (hx0 ^ hy1 ^ hz1) & (TSIZE - 1u);
                idx[4] = (hx1 ^ hy0 ^ hz0) & (TSIZE - 1u);
                idx[5] = (hx1 ^ hy0 ^ hz1) & (TSIZE - 1u);
                idx[6] = (hx1 ^ hy1 ^ hz0) & (TSIZE - 1u);
                idx[7] = (hx1 ^ hy1 ^ hz1) & (TSIZE - 1u);
            }

            const float2* tl = reinterpret_cast<const float2*>(table) + (size_t)l * TSIZE;
            float2 g[8];
#pragma unroll
            for (int k = 0; k < 8; ++k) g[k] = tl[idx[k]];

            const float wa0 = 1.0f - ra, wa1 = ra;
            const float wb0 = 1.0f - rb, wb1 = rb;
            const float wc0 = 1.0f - rc, wc1 = rc;
            float e0 = 0.0f, e1 = 0.0f;
#pragma unroll
            for (int k = 0; k < 8; ++k) {
                const float w = ((k & 4) ? wa1 : wa0) * ((k & 2) ? wb1 : wb0) * ((k & 1) ? wc1 : wc0);
                e0 = fmaf(w, g[k].x, e0);
                e1 = fmaf(w, g[k].y, e1);
            }
            enc[2 * l] = e0;
            enc[2 * l + 1] = e1;
        }
    }

    {
        float4* encV = reinterpret_cast<float4*>(enc);
        float4* row = reinterpret_cast<float4*>(&encS[tid * 32]);
        const int sw = tid & 7;
#pragma unroll
        for (int k = 0; k < 8; ++k) row[k ^ sw] = encV[k];
    }

    const int lane = tid & 63;
    const int wv = tid >> 6;
    const int j0 = lane & 31;
    const int half = lane >> 5;

    float Wreg0[RAW], Wreg1[RAW];
    {
        const float4* W4 = reinterpret_cast<const float4*>(W);
        float4* w0 = reinterpret_cast<float4*>(Wreg0);
        float4* w1 = reinterpret_cast<float4*>(Wreg1);
#pragma unroll
        for (int k = 0; k < 8; ++k) {
            w0[k] = W4[j0 * 8 + k];
            w1[k] = W4[(j0 + 32) * 8 + k];
        }
    }
    const float b0 = bias[j0];
    const float b1 = bias[j0 + 32];

    __syncthreads();

    const size_t outBase = (size_t)blockIdx.x * 256 * ODIM;
#pragma unroll 2
    for (int i = 0; i < 32; ++i) {
        const int q = wv * 64 + 2 * i + half;
        const float4* er = reinterpret_cast<const float4*>(&encS[q * 32]);
        const int qsw = q & 7;
        float acc0 = b0, acc1 = b1;
#pragma unroll
        for (int k4 = 0; k4 < 8; ++k4) {
            const float4 e = er[k4 ^ qsw];
            acc0 = fmaf(e.x, Wreg0[4 * k4 + 0], acc0);
            acc1 = fmaf(e.x, Wreg1[4 * k4 + 1 - 1], acc1);
            acc0 = fmaf(e.y, Wreg0[4 * k4 + 1], acc0);
            acc1 = fmaf(e.y, Wreg1[4 * k4 + 1], acc1);
            acc0 = fmaf(e.z, Wreg0[4 * k4 + 2], acc0);
            acc1 = fmaf(e.z, Wreg1[4 * k4 + 2], acc1);
            acc0 = fmaf(e.w, Wreg0[4 * k4 + 3], acc0);
            acc1 = fmaf(e.w, Wreg1[4 * k4 + 3], acc1);
        }
        float* o = out + outBase + (size_t)q * ODIM;
        __builtin_nontemporal_store(acc0, &o[j0]);
        __builtin_nontemporal_store(acc1, &o[j0 + 32]);
    }
}

extern "C" void kernel_launch(void* const* d_in, const int* in_sizes, int n_in,
                              void* d_out, int out_size, void* d_ws, size_t ws_size,
                              hipStream_t stream) {
    const float* x = (const float*)d_in[0];      // [B,N,3]
    const float* table = (const float*)d_in[1];  // [L,T,F]
    const float* W = (const float*)d_in[2];      // [64,32]
    const float* b = (const float*)d_in[3];      // [64]
    float* out = (float*)d_out;                  // [B,N,64]

    const int P = in_sizes[0] / 3;               // 1048576, multiple of 256
    const int blocks = P / 256;
    const size_t need = (size_t)P * RAW * sizeof(float);  // 128 MB partial enc

    if (ws_size >= need) {
        float* encPart = (float*)d_ws;           // [8][P][4] f32
        hipLaunchKernelGGL(hashgrid_part, dim3(blocks * 8), dim3(256), 0, stream,
                           x, table, encPart, P);
        hipLaunchKernelGGL(linear_out, dim3(blocks), dim3(256), 0, stream,
                           encPart, W, b, out, P);
    } else {
        hipLaunchKernelGGL(hashgrid_fused, dim3(blocks), dim3(256), 0, stream,
                           x, table, W, b, out);
    }
}

// Round 3
// 872.781 us; speedup vs baseline: 1.4388x; 1.2953x over previous
//
#include <hip/hip_runtime.h>
#include <stdint.h>

// HashGridEncoding: tcnn hashgrid (L=16, F=2, T=2^19, base=16, scale=1.5)
// fused with Linear(32 -> 64). fp32 in/out.
//
// R3: full level-per-XCD partitioning (R2 halved fetch with level-PAIR-per-XCD;
// residual misses came exactly from the 8MB-working-set XCDs).
//   k1 pass A: XCD g (blockIdx&7) owns hashed level 4+g  -> 4MB table L2-resident.
//   k1 pass B: XCDs 0-3 own hashed levels 12-15; XCDs 4-7 own dense levels 0-3.
//   Each thread: one level, two points. nt loads (x) + nt stores (encPart) so the
//   streams don't evict the resident table.
//   k2: assemble enc in natural order (bit-identical FMA sequence),
//       Linear(32->64) via LDS broadcast + W rows in VGPRs.
//       R2's 353us k2 was a VGPR spill from __launch_bounds__(256,5) (48 VGPR vs
//       96+ live floats -> W arrays in scratch). Plain launch_bounds(256) fixes it.

constexpr int LVLS = 16;
constexpr uint32_t TSIZE = 1u << 19;
constexpr int RAW = 32;   // L*F
constexpr int ODIM = 64;

typedef float vfloat2 __attribute__((ext_vector_type(2)));

// scale_l = 16*1.5^l - 1 (exactly representable in f32); res_l = ceil(scale)+1
__constant__ float kScaleC[LVLS] = {
    15.0f, 23.0f, 35.0f, 53.0f, 80.0f, 120.5f, 181.25f, 272.375f,
    409.0625f, 614.09375f, 921.640625f, 1382.9609375f,
    2074.94140625f, 3112.912109375f, 4669.8681640625f, 7005.30224609375f};
__constant__ uint32_t kResC[LVLS] = {
    16, 24, 36, 54, 81, 122, 183, 274, 411, 616, 923, 1384, 2076, 3114, 4671, 7007};

__device__ __forceinline__ uint32_t umin32(uint32_t a, uint32_t b) { return a < b ? a : b; }

// One level's trilinear-interpolated float2 feature. l is wave-uniform.
__device__ __forceinline__ void enc_level(
    int l, float xn0, float xn1, float xn2,
    const float* __restrict__ table, float& e0out, float& e1out)
{
    const float s = kScaleC[l];
    const uint32_t res = kResC[l];

    const float pa = xn0 * s + 0.5f;
    const float pb = xn1 * s + 0.5f;
    const float pc = xn2 * s + 0.5f;
    const float fa = floorf(pa);
    const float fb = floorf(pb);
    const float fc = floorf(pc);
    const float ra = pa - fa;
    const float rb = pb - fb;
    const float rc = pc - fc;
    const uint32_t ca = (uint32_t)fa;
    const uint32_t cb = (uint32_t)fb;
    const uint32_t cc = (uint32_t)fc;

    uint32_t idx[8];
    if (l < 4) {
        // dense: idx = cx + cy*res + cz*res^2, coords clamped to res-1
        const uint32_t rm = res - 1u;
        const uint32_t rr = res * res;
        const uint32_t x0 = umin32(ca, rm);
        const uint32_t x1 = umin32(ca + 1u, rm);
        const uint32_t y0 = umin32(cb, rm) * res;
        const uint32_t y1 = umin32(cb + 1u, rm) * res;
        const uint32_t z0 = umin32(cc, rm) * rr;
        const uint32_t z1 = umin32(cc + 1u, rm) * rr;
        idx[0] = x0 + y0 + z0;
        idx[1] = x0 + y0 + z1;
        idx[2] = x0 + y1 + z0;
        idx[3] = x0 + y1 + z1;
        idx[4] = x1 + y0 + z0;
        idx[5] = x1 + y0 + z1;
        idx[6] = x1 + y1 + z0;
        idx[7] = x1 + y1 + z1;
    } else {
        // hashed: (cx*1) ^ (cy*2654435761) ^ (cz*805459861), mod T
        const uint32_t hx0 = ca;
        const uint32_t hx1 = ca + 1u;
        const uint32_t hy0 = cb * 2654435761u;
        const uint32_t hy1 = hy0 + 2654435761u;
        const uint32_t hz0 = cc * 805459861u;
        const uint32_t hz1 = hz0 + 805459861u;
        idx[0] = (hx0 ^ hy0 ^ hz0) & (TSIZE - 1u);
        idx[1] = (hx0 ^ hy0 ^ hz1) & (TSIZE - 1u);
        idx[2] = (hx0 ^ hy1 ^ hz0) & (TSIZE - 1u);
        idx[3] = (hx0 ^ hy1 ^ hz1) & (TSIZE - 1u);
        idx[4] = (hx1 ^ hy0 ^ hz0) & (TSIZE - 1u);
        idx[5] = (hx1 ^ hy0 ^ hz1) & (TSIZE - 1u);
        idx[6] = (hx1 ^ hy1 ^ hz0) & (TSIZE - 1u);
        idx[7] = (hx1 ^ hy1 ^ hz1) & (TSIZE - 1u);
    }

    const float2* tl = reinterpret_cast<const float2*>(table) + (size_t)l * TSIZE;
    float2 g[8];
#pragma unroll
    for (int k = 0; k < 8; ++k) g[k] = tl[idx[k]];

    const float wa0 = 1.0f - ra, wa1 = ra;
    const float wb0 = 1.0f - rb, wb1 = rb;
    const float wc0 = 1.0f - rc, wc1 = rc;
    float e0 = 0.0f, e1 = 0.0f;
#pragma unroll
    for (int k = 0; k < 8; ++k) {
        const float w = ((k & 4) ? wa1 : wa0) * ((k & 2) ? wb1 : wb0) * ((k & 1) ? wc1 : wc0);
        e0 = fmaf(w, g[k].x, e0);
        e1 = fmaf(w, g[k].y, e1);
    }
    e0out = e0;
    e1out = e1;
}

// Kernel 1 (run twice): grid (P/512)*8. slot = blockIdx&7 -> XCD slot.
// passB=0: level = 4+slot (hashed 4..11).  passB=1: slot<4 -> 12+slot (hashed),
// slot>=4 -> slot-4 (dense 0..3). Each thread: 1 level, 2 points.
__global__ __launch_bounds__(256) void hashgrid_lvl(
    const float* __restrict__ x,
    const float* __restrict__ table,
    float* __restrict__ encPart,
    int P, int passB)
{
    const int slot = blockIdx.x & 7;
    const int chunk = blockIdx.x >> 3;
    const int tid = threadIdx.x;
    const int l = passB ? (slot < 4 ? 12 + slot : slot - 4) : 4 + slot;

    const int p0 = chunk * 512 + tid;
    const int p1 = p0 + 256;

    const float a0 = __builtin_nontemporal_load(&x[3 * p0 + 0]);
    const float a1 = __builtin_nontemporal_load(&x[3 * p0 + 1]);
    const float a2 = __builtin_nontemporal_load(&x[3 * p0 + 2]);
    const float b0 = __builtin_nontemporal_load(&x[3 * p1 + 0]);
    const float b1 = __builtin_nontemporal_load(&x[3 * p1 + 1]);
    const float b2 = __builtin_nontemporal_load(&x[3 * p1 + 2]);

    float e00, e01, e10, e11;
    enc_level(l, (a0 + 1.0f) * 0.5f, (a1 + 1.0f) * 0.5f, (a2 + 1.0f) * 0.5f,
              table, e00, e01);
    enc_level(l, (b0 + 1.0f) * 0.5f, (b1 + 1.0f) * 0.5f, (b2 + 1.0f) * 0.5f,
              table, e10, e11);

    vfloat2* dst = reinterpret_cast<vfloat2*>(encPart) + (size_t)l * P;
    vfloat2 v0 = {e00, e01};
    vfloat2 v1 = {e10, e11};
    __builtin_nontemporal_store(v0, dst + p0);   // streaming, read-once by k2
    __builtin_nontemporal_store(v1, dst + p1);
}

// Kernel 2: assemble enc (natural order), Linear(32->64) via LDS broadcast.
__global__ __launch_bounds__(256) void linear_out(
    const float* __restrict__ encPart,
    const float* __restrict__ W,
    const float* __restrict__ bias,
    float* __restrict__ out,
    int P)
{
    __shared__ float encS[256 * 32];  // 32 KiB, XOR-swizzled float4 slots

    const int tid = threadIdx.x;
    const int p = blockIdx.x * 256 + tid;

    float enc[RAW];
    {
        const vfloat2* ep = reinterpret_cast<const vfloat2*>(encPart);
#pragma unroll
        for (int l = 0; l < LVLS; ++l) {
            const vfloat2 v = __builtin_nontemporal_load(ep + (size_t)l * P + p);
            enc[2 * l + 0] = v.x;
            enc[2 * l + 1] = v.y;
        }
    }

    // stage enc -> LDS: row tid, float4 slot k stored at (k ^ (tid&7))
    {
        float4* encV = reinterpret_cast<float4*>(enc);
        float4* row = reinterpret_cast<float4*>(&encS[tid * 32]);
        const int sw = tid & 7;
#pragma unroll
        for (int k = 0; k < 8; ++k) row[k ^ sw] = encV[k];
    }

    // per-lane W rows (j0 and j0+32) into VGPRs
    const int lane = tid & 63;
    const int wv = tid >> 6;
    const int j0 = lane & 31;
    const int half = lane >> 5;

    float Wreg0[RAW], Wreg1[RAW];
    {
        const float4* W4 = reinterpret_cast<const float4*>(W);
        float4* w0 = reinterpret_cast<float4*>(Wreg0);
        float4* w1 = reinterpret_cast<float4*>(Wreg1);
#pragma unroll
        for (int k = 0; k < 8; ++k) {
            w0[k] = W4[j0 * 8 + k];
            w1[k] = W4[(j0 + 32) * 8 + k];
        }
    }
    const float b0 = bias[j0];
    const float b1 = bias[j0 + 32];

    __syncthreads();

    const size_t outBase = (size_t)blockIdx.x * 256 * ODIM;
#pragma unroll 2
    for (int i = 0; i < 32; ++i) {
        const int q = wv * 64 + 2 * i + half;
        const float4* er = reinterpret_cast<const float4*>(&encS[q * 32]);
        const int qsw = q & 7;
        float acc0 = b0, acc1 = b1;
#pragma unroll
        for (int k4 = 0; k4 < 8; ++k4) {
            const float4 e = er[k4 ^ qsw];
            acc0 = fmaf(e.x, Wreg0[4 * k4 + 0], acc0);
            acc1 = fmaf(e.x, Wreg1[4 * k4 + 0], acc1);
            acc0 = fmaf(e.y, Wreg0[4 * k4 + 1], acc0);
            acc1 = fmaf(e.y, Wreg1[4 * k4 + 1], acc1);
            acc0 = fmaf(e.z, Wreg0[4 * k4 + 2], acc0);
            acc1 = fmaf(e.z, Wreg1[4 * k4 + 2], acc1);
            acc0 = fmaf(e.w, Wreg0[4 * k4 + 3], acc0);
            acc1 = fmaf(e.w, Wreg1[4 * k4 + 3], acc1);
        }
        float* o = out + outBase + (size_t)q * ODIM;
        __builtin_nontemporal_store(acc0, &o[j0]);
        __builtin_nontemporal_store(acc1, &o[j0 + 32]);
    }
}

// ---------------- fallback: single fused kernel (used if workspace too small) --

__global__ __launch_bounds__(256) void hashgrid_fused(
    const float* __restrict__ x,
    const float* __restrict__ table,
    const float* __restrict__ W,
    const float* __restrict__ bias,
    float* __restrict__ out)
{
    __shared__ float encS[256 * 32];

    const int tid = threadIdx.x;
    const int p = blockIdx.x * 256 + tid;

    float enc[RAW];

    {
        const float xr0 = x[3 * p + 0];
        const float xr1 = x[3 * p + 1];
        const float xr2 = x[3 * p + 2];
        const float xn0 = (xr0 + 1.0f) * 0.5f;
        const float xn1 = (xr1 + 1.0f) * 0.5f;
        const float xn2 = (xr2 + 1.0f) * 0.5f;

#pragma unroll
        for (int l = 0; l < LVLS; ++l) {
            float e0, e1;
            enc_level(l, xn0, xn1, xn2, table, e0, e1);
            enc[2 * l] = e0;
            enc[2 * l + 1] = e1;
        }
    }

    {
        float4* encV = reinterpret_cast<float4*>(enc);
        float4* row = reinterpret_cast<float4*>(&encS[tid * 32]);
        const int sw = tid & 7;
#pragma unroll
        for (int k = 0; k < 8; ++k) row[k ^ sw] = encV[k];
    }

    const int lane = tid & 63;
    const int wv = tid >> 6;
    const int j0 = lane & 31;
    const int half = lane >> 5;

    float Wreg0[RAW], Wreg1[RAW];
    {
        const float4* W4 = reinterpret_cast<const float4*>(W);
        float4* w0 = reinterpret_cast<float4*>(Wreg0);
        float4* w1 = reinterpret_cast<float4*>(Wreg1);
#pragma unroll
        for (int k = 0; k < 8; ++k) {
            w0[k] = W4[j0 * 8 + k];
            w1[k] = W4[(j0 + 32) * 8 + k];
        }
    }
    const float b0 = bias[j0];
    const float b1 = bias[j0 + 32];

    __syncthreads();

    const size_t outBase = (size_t)blockIdx.x * 256 * ODIM;
#pragma unroll 2
    for (int i = 0; i < 32; ++i) {
        const int q = wv * 64 + 2 * i + half;
        const float4* er = reinterpret_cast<const float4*>(&encS[q * 32]);
        const int qsw = q & 7;
        float acc0 = b0, acc1 = b1;
#pragma unroll
        for (int k4 = 0; k4 < 8; ++k4) {
            const float4 e = er[k4 ^ qsw];
            acc0 = fmaf(e.x, Wreg0[4 * k4 + 0], acc0);
            acc1 = fmaf(e.x, Wreg1[4 * k4 + 0], acc1);
            acc0 = fmaf(e.y, Wreg0[4 * k4 + 1], acc0);
            acc1 = fmaf(e.y, Wreg1[4 * k4 + 1], acc1);
            acc0 = fmaf(e.z, Wreg0[4 * k4 + 2], acc0);
            acc1 = fmaf(e.z, Wreg1[4 * k4 + 2], acc1);
            acc0 = fmaf(e.w, Wreg0[4 * k4 + 3], acc0);
            acc1 = fmaf(e.w, Wreg1[4 * k4 + 3], acc1);
        }
        float* o = out + outBase + (size_t)q * ODIM;
        __builtin_nontemporal_store(acc0, &o[j0]);
        __builtin_nontemporal_store(acc1, &o[j0 + 32]);
    }
}

extern "C" void kernel_launch(void* const* d_in, const int* in_sizes, int n_in,
                              void* d_out, int out_size, void* d_ws, size_t ws_size,
                              hipStream_t stream) {
    const float* x = (const float*)d_in[0];      // [B,N,3]
    const float* table = (const float*)d_in[1];  // [L,T,F]
    const float* W = (const float*)d_in[2];      // [64,32]
    const float* b = (const float*)d_in[3];      // [64]
    float* out = (float*)d_out;                  // [B,N,64]

    const int P = in_sizes[0] / 3;               // 1048576, multiple of 512
    const int blocks = P / 256;
    const size_t need = (size_t)P * RAW * sizeof(float);  // 128 MB partial enc

    if (ws_size >= need && (P % 512) == 0) {
        float* encPart = (float*)d_ws;           // [16][P] float2
        const int b16 = (P / 512) * 8;
        hipLaunchKernelGGL(hashgrid_lvl, dim3(b16), dim3(256), 0, stream,
                           x, table, encPart, P, 0);
        hipLaunchKernelGGL(hashgrid_lvl, dim3(b16), dim3(256), 0, stream,
                           x, table, encPart, P, 1);
        hipLaunchKernelGGL(linear_out, dim3(blocks), dim3(256), 0, stream,
                           encPart, W, b, out, P);
    } else {
        hipLaunchKernelGGL(hashgrid_fused, dim3(blocks), dim3(256), 0, stream,
                           x, table, W, b, out);
    }
}